// Round 1
// baseline (1923.589 us; speedup 1.0000x reference)
//
#include <hip/hip_runtime.h>

#define T_STEPS 512
#define B_SZ    64
#define DIN     128
#define DH      1024
#define DOUT    256
#define RNK     64
#define HID_ELEMS ((size_t)T_STEPS * B_SZ * DH)   // 33554432

// ---------------------------------------------------------------------------
// K1: zi[tb, h] = sum_k x[tb,k] * Wi[h,k] + bh[h]   -> stored into hidden region
// [32768,128] x [128,1024], tile 64x64, K chunks of 64.
// ---------------------------------------------------------------------------
__global__ __launch_bounds__(256) void k1_zi(
    const float* __restrict__ x, const float* __restrict__ Wi,
    const float* __restrict__ bh, float* __restrict__ zi)
{
    __shared__ float At[64][68];   // K-major x tile   (pad keeps 16B row align: 68*4=272)
    __shared__ float Bt[64][68];   // K-major Wi tile
    const int m0 = blockIdx.y * 64;
    const int n0 = blockIdx.x * 64;
    const int tid = threadIdx.x;
    const int tx = tid & 15, ty = tid >> 4;
    float acc[4][4] = {};

    for (int kc = 0; kc < DIN; kc += 64) {
        #pragma unroll
        for (int i = 0; i < 4; ++i) {            // x tile: 64 rows x 64 k
            int idx = tid + i * 256;             // float4 index in [0,1024)
            int row = idx >> 4;
            int c4  = idx & 15;
            float4 v = *reinterpret_cast<const float4*>(&x[(size_t)(m0 + row) * DIN + kc + c4 * 4]);
            At[c4*4+0][row] = v.x; At[c4*4+1][row] = v.y;
            At[c4*4+2][row] = v.z; At[c4*4+3][row] = v.w;
        }
        #pragma unroll
        for (int i = 0; i < 4; ++i) {            // Wi tile: 64 rows x 64 k
            int idx = tid + i * 256;
            int row = idx >> 4;
            int c4  = idx & 15;
            float4 v = *reinterpret_cast<const float4*>(&Wi[(size_t)(n0 + row) * DIN + kc + c4 * 4]);
            Bt[c4*4+0][row] = v.x; Bt[c4*4+1][row] = v.y;
            Bt[c4*4+2][row] = v.z; Bt[c4*4+3][row] = v.w;
        }
        __syncthreads();
        #pragma unroll
        for (int k = 0; k < 64; ++k) {
            float4 a = *reinterpret_cast<const float4*>(&At[k][ty * 4]);
            float4 b = *reinterpret_cast<const float4*>(&Bt[k][tx * 4]);
            float av[4] = {a.x, a.y, a.z, a.w};
            float bv[4] = {b.x, b.y, b.z, b.w};
            #pragma unroll
            for (int i = 0; i < 4; ++i)
                #pragma unroll
                for (int j = 0; j < 4; ++j)
                    acc[i][j] = fmaf(av[i], bv[j], acc[i][j]);
        }
        __syncthreads();
    }
    float4 bias = *reinterpret_cast<const float4*>(&bh[n0 + tx * 4]);
    #pragma unroll
    for (int i = 0; i < 4; ++i) {
        float4 o;
        o.x = acc[i][0] + bias.x; o.y = acc[i][1] + bias.y;
        o.z = acc[i][2] + bias.z; o.w = acc[i][3] + bias.w;
        *reinterpret_cast<float4*>(&zi[(size_t)(m0 + ty * 4 + i) * DH + n0 + tx * 4]) = o;
    }
}

// ---------------------------------------------------------------------------
// K2: sequential recurrence. One workgroup per batch element (64 WGs, 512 thr).
// State r = h @ V.T  (RANK=64 floats) lives distributed across the 64 lanes of
// every wave (1 VGPR), broadcast with v_readlane. hid[] holds zi+bh on entry
// for step t and is overwritten with h_t (read-before-write within the step).
// ---------------------------------------------------------------------------
__global__ __launch_bounds__(512) void k2_rec(
    const float* __restrict__ U, const float* __restrict__ V,
    float* __restrict__ hid)
{
    __shared__ float h_lds[DH];
    __shared__ float red[8][64];
    const int b    = blockIdx.x;
    const int tid  = threadIdx.x;
    const int lane = tid & 63;
    const int g    = tid >> 6;          // wave id 0..7
    const int j0   = tid, j1 = tid + 512;
    const float4* __restrict__ U4 = reinterpret_cast<const float4*>(U);
    const float4* __restrict__ V4 = reinterpret_cast<const float4*>(V);
    float rv = 0.0f;                     // lane l holds r_l

    for (int t = 0; t < T_STEPS; ++t) {
        const size_t base = ((size_t)t * B_SZ + b) * DH;
        float e0 = hid[base + j0];       // zi + bh
        float e1 = hid[base + j1];
        // expand: e_j += sum_k r_k * U[j,k]
        #pragma unroll
        for (int kk = 0; kk < 16; ++kk) {
            float4 u0 = U4[j0 * 16 + kk];
            float4 u1 = U4[j1 * 16 + kk];
            float r0 = __uint_as_float(__builtin_amdgcn_readlane(__float_as_uint(rv), kk * 4 + 0));
            float r1 = __uint_as_float(__builtin_amdgcn_readlane(__float_as_uint(rv), kk * 4 + 1));
            float r2 = __uint_as_float(__builtin_amdgcn_readlane(__float_as_uint(rv), kk * 4 + 2));
            float r3 = __uint_as_float(__builtin_amdgcn_readlane(__float_as_uint(rv), kk * 4 + 3));
            e0 = fmaf(r0, u0.x, e0); e1 = fmaf(r0, u1.x, e1);
            e0 = fmaf(r1, u0.y, e0); e1 = fmaf(r1, u1.y, e1);
            e0 = fmaf(r2, u0.z, e0); e1 = fmaf(r2, u1.z, e1);
            e0 = fmaf(r3, u0.w, e0); e1 = fmaf(r3, u1.w, e1);
        }
        float h0 = fmaxf(e0, 0.0f);
        float h1 = fmaxf(e1, 0.0f);
        h_lds[j0] = h0; h_lds[j1] = h1;
        hid[base + j0] = h0;             // hidden output (coalesced)
        hid[base + j1] = h1;
        __syncthreads();
        // contract: wave g reduces j-slice [g*128, g*128+128), lane = output k
        float a = 0.0f;
        #pragma unroll
        for (int jj = 0; jj < 32; ++jj) {
            float4 hv = *reinterpret_cast<const float4*>(&h_lds[g * 128 + jj * 4]);
            float4 vv = V4[lane * (DH/4) + g * 32 + jj];
            a = fmaf(hv.x, vv.x, a);
            a = fmaf(hv.y, vv.y, a);
            a = fmaf(hv.z, vv.z, a);
            a = fmaf(hv.w, vv.w, a);
        }
        red[g][lane] = a;
        __syncthreads();
        rv = red[0][lane] + red[1][lane] + red[2][lane] + red[3][lane]
           + red[4][lane] + red[5][lane] + red[6][lane] + red[7][lane];
        // next-iteration red writes are fenced by the next sync after h-store
    }
}

// ---------------------------------------------------------------------------
// K3: out[tb, n] = sum_k hid[tb,k] * Wo[n,k] + bo[n]
// [32768,1024] x [1024,256], tile 128x64, K chunks of 64, 8x4 micro-tile.
// ---------------------------------------------------------------------------
__global__ __launch_bounds__(256) void k3_out(
    const float* __restrict__ hid, const float* __restrict__ Wo,
    const float* __restrict__ bo, float* __restrict__ out)
{
    __shared__ float At[64][136];  // K-major hid tile, 128 m cols (+8 pad, 544B rows)
    __shared__ float Bt[64][68];   // K-major Wo tile
    const int m0 = blockIdx.y * 128;
    const int n0 = blockIdx.x * 64;
    const int tid = threadIdx.x;
    const int tx = tid & 15, ty = tid >> 4;
    float acc[8][4] = {};

    for (int kc = 0; kc < DH; kc += 64) {
        #pragma unroll
        for (int i = 0; i < 8; ++i) {            // hid tile: 128 rows x 64 k
            int idx = tid + i * 256;             // float4 idx in [0,2048)
            int row = idx >> 4;
            int c4  = idx & 15;
            float4 v = *reinterpret_cast<const float4*>(&hid[(size_t)(m0 + row) * DH + kc + c4 * 4]);
            At[c4*4+0][row] = v.x; At[c4*4+1][row] = v.y;
            At[c4*4+2][row] = v.z; At[c4*4+3][row] = v.w;
        }
        #pragma unroll
        for (int i = 0; i < 4; ++i) {            // Wo tile: 64 rows x 64 k
            int idx = tid + i * 256;
            int row = idx >> 4;
            int c4  = idx & 15;
            float4 v = *reinterpret_cast<const float4*>(&Wo[(size_t)(n0 + row) * DH + kc + c4 * 4]);
            Bt[c4*4+0][row] = v.x; Bt[c4*4+1][row] = v.y;
            Bt[c4*4+2][row] = v.z; Bt[c4*4+3][row] = v.w;
        }
        __syncthreads();
        #pragma unroll
        for (int k = 0; k < 64; ++k) {
            float4 a0 = *reinterpret_cast<const float4*>(&At[k][ty * 8]);
            float4 a1 = *reinterpret_cast<const float4*>(&At[k][ty * 8 + 4]);
            float4 b  = *reinterpret_cast<const float4*>(&Bt[k][tx * 4]);
            float av[8] = {a0.x, a0.y, a0.z, a0.w, a1.x, a1.y, a1.z, a1.w};
            float bv[4] = {b.x, b.y, b.z, b.w};
            #pragma unroll
            for (int i = 0; i < 8; ++i)
                #pragma unroll
                for (int j = 0; j < 4; ++j)
                    acc[i][j] = fmaf(av[i], bv[j], acc[i][j]);
        }
        __syncthreads();
    }
    float4 bias = *reinterpret_cast<const float4*>(&bo[n0 + tx * 4]);
    #pragma unroll
    for (int i = 0; i < 8; ++i) {
        float4 o;
        o.x = acc[i][0] + bias.x; o.y = acc[i][1] + bias.y;
        o.z = acc[i][2] + bias.z; o.w = acc[i][3] + bias.w;
        *reinterpret_cast<float4*>(&out[(size_t)(m0 + ty * 8 + i) * DOUT + n0 + tx * 4]) = o;
    }
}

// ---------------------------------------------------------------------------
extern "C" void kernel_launch(void* const* d_in, const int* in_sizes, int n_in,
                              void* d_out, int out_size, void* d_ws, size_t ws_size,
                              hipStream_t stream)
{
    const float* x  = (const float*)d_in[0];
    const float* Wi = (const float*)d_in[1];
    const float* U  = (const float*)d_in[2];
    const float* V  = (const float*)d_in[3];
    const float* bh = (const float*)d_in[4];
    const float* Wo = (const float*)d_in[5];
    const float* bo = (const float*)d_in[6];
    float* hid  = (float*)d_out;              // hidden region, also zi staging
    float* outp = (float*)d_out + HID_ELEMS;  // output region

    // Phase 1: zi + bh -> hidden region
    k1_zi<<<dim3(DH / 64, (T_STEPS * B_SZ) / 64), 256, 0, stream>>>(x, Wi, bh, hid);
    // Phase 2: recurrence (overwrites zi with hidden), 1 WG per batch element
    k2_rec<<<dim3(B_SZ), 512, 0, stream>>>(U, V, hid);
    // Phase 3: output projection
    k3_out<<<dim3(DOUT / 64, (T_STEPS * B_SZ) / 128), 256, 0, stream>>>(hid, Wo, bo, outp);
}

// Round 2
// 1300.379 us; speedup vs baseline: 1.4793x; 1.4793x over previous
//
#include <hip/hip_runtime.h>

#define T_STEPS 512
#define B_SZ    64
#define DIN     128
#define DH      1024
#define DOUT    256
#define RNK     64
#define HID_ELEMS ((size_t)T_STEPS * B_SZ * DH)   // 33554432

typedef _Float16 h2 __attribute__((ext_vector_type(2)));

// ---------------------------------------------------------------------------
// K1: zi[tb, h] = sum_k x[tb,k] * Wi[h,k] + bh[h]   -> stored into hidden region
// ---------------------------------------------------------------------------
__global__ __launch_bounds__(256) void k1_zi(
    const float* __restrict__ x, const float* __restrict__ Wi,
    const float* __restrict__ bh, float* __restrict__ zi)
{
    __shared__ float At[64][68];
    __shared__ float Bt[64][68];
    const int m0 = blockIdx.y * 64;
    const int n0 = blockIdx.x * 64;
    const int tid = threadIdx.x;
    const int tx = tid & 15, ty = tid >> 4;
    float acc[4][4] = {};

    for (int kc = 0; kc < DIN; kc += 64) {
        #pragma unroll
        for (int i = 0; i < 4; ++i) {
            int idx = tid + i * 256;
            int row = idx >> 4;
            int c4  = idx & 15;
            float4 v = *reinterpret_cast<const float4*>(&x[(size_t)(m0 + row) * DIN + kc + c4 * 4]);
            At[c4*4+0][row] = v.x; At[c4*4+1][row] = v.y;
            At[c4*4+2][row] = v.z; At[c4*4+3][row] = v.w;
        }
        #pragma unroll
        for (int i = 0; i < 4; ++i) {
            int idx = tid + i * 256;
            int row = idx >> 4;
            int c4  = idx & 15;
            float4 v = *reinterpret_cast<const float4*>(&Wi[(size_t)(n0 + row) * DIN + kc + c4 * 4]);
            Bt[c4*4+0][row] = v.x; Bt[c4*4+1][row] = v.y;
            Bt[c4*4+2][row] = v.z; Bt[c4*4+3][row] = v.w;
        }
        __syncthreads();
        #pragma unroll
        for (int k = 0; k < 64; ++k) {
            float4 a = *reinterpret_cast<const float4*>(&At[k][ty * 4]);
            float4 b = *reinterpret_cast<const float4*>(&Bt[k][tx * 4]);
            float av[4] = {a.x, a.y, a.z, a.w};
            float bv[4] = {b.x, b.y, b.z, b.w};
            #pragma unroll
            for (int i = 0; i < 4; ++i)
                #pragma unroll
                for (int j = 0; j < 4; ++j)
                    acc[i][j] = fmaf(av[i], bv[j], acc[i][j]);
        }
        __syncthreads();
    }
    float4 bias = *reinterpret_cast<const float4*>(&bh[n0 + tx * 4]);
    #pragma unroll
    for (int i = 0; i < 4; ++i) {
        float4 o;
        o.x = acc[i][0] + bias.x; o.y = acc[i][1] + bias.y;
        o.z = acc[i][2] + bias.z; o.w = acc[i][3] + bias.w;
        *reinterpret_cast<float4*>(&zi[(size_t)(m0 + ty * 4 + i) * DH + n0 + tx * 4]) = o;
    }
}

// ---------------------------------------------------------------------------
// K2 v2: register-resident weights.
//   - U rows (fp32, 128 VGPRs) for the expand (full-precision recurrent path)
//   - V slice (fp16 packed, 64 VGPRs) for the contract via v_dot2_f32_f16
//   - r state distributed across 64 lanes of every wave; broadcast by readlane
//   - h exchanged through LDS as fp16; zi for step t+1 prefetched during t
// One WG (512 thr = 8 waves) per batch element. No per-step weight traffic.
// ---------------------------------------------------------------------------
__global__ __launch_bounds__(512, 2) void k2_rec(
    const float* __restrict__ U, const float* __restrict__ V,
    float* __restrict__ hid)
{
    __shared__ _Float16 h16[DH];
    __shared__ float red[8][64];
    const int b    = blockIdx.x;
    const int tid  = threadIdx.x;
    const int lane = tid & 63;
    const int g    = tid >> 6;          // wave id 0..7
    const int j0   = tid, j1 = tid + 512;

    // ---- one-time: weights into registers ----
    float u0[64], u1[64];
    const float4* __restrict__ U4 = reinterpret_cast<const float4*>(U);
    #pragma unroll
    for (int q = 0; q < 16; ++q) {
        float4 a = U4[j0 * 16 + q];
        u0[q*4+0]=a.x; u0[q*4+1]=a.y; u0[q*4+2]=a.z; u0[q*4+3]=a.w;
        float4 c = U4[j1 * 16 + q];
        u1[q*4+0]=c.x; u1[q*4+1]=c.y; u1[q*4+2]=c.z; u1[q*4+3]=c.w;
    }
    h2 vh[64];                           // V[lane][g*128 + 2m .. +1], packed fp16
    {
        const float2* __restrict__ vrow =
            reinterpret_cast<const float2*>(V + (size_t)lane * DH + g * 128);
        #pragma unroll
        for (int m = 0; m < 64; ++m) {
            float2 f = vrow[m];
            h2 p; p.x = (_Float16)f.x; p.y = (_Float16)f.y;
            vh[m] = p;
        }
    }

    float rv = 0.0f;                     // lane l holds r_l (h0 = 0 -> r = 0)
    size_t base = (size_t)b * DH;
    float z0 = hid[base + j0];           // zi + bh for t = 0
    float z1 = hid[base + j1];

    for (int t = 0; t < T_STEPS; ++t) {
        // expand: e_j = zi_j + sum_k r_k * U[j,k]   (fp32)
        float e0 = z0, e1 = z1;
        #pragma unroll
        for (int kk = 0; kk < 64; ++kk) {
            float rk = __uint_as_float(__builtin_amdgcn_readlane(__float_as_uint(rv), kk));
            e0 = fmaf(rk, u0[kk], e0);
            e1 = fmaf(rk, u1[kk], e1);
        }
        float h0 = fmaxf(e0, 0.0f);
        float h1 = fmaxf(e1, 0.0f);
        hid[base + j0] = h0;             // hidden output (fp32, coalesced)
        hid[base + j1] = h1;
        h16[j0] = (_Float16)h0;          // LDS exchange for contract
        h16[j1] = (_Float16)h1;
        if (t + 1 < T_STEPS) {           // prefetch next zi (region untouched yet)
            size_t nbase = base + (size_t)B_SZ * DH;
            z0 = hid[nbase + j0];
            z1 = hid[nbase + j1];
        }
        __syncthreads();                 // h16 ready
        // contract: wave g, lane k: a = sum_{jj<128} h[g*128+jj] * V[k][g*128+jj]
        float acc = 0.0f;
        const h2* __restrict__ hp = reinterpret_cast<const h2*>(&h16[g * 128]);
        #pragma unroll
        for (int m = 0; m < 64; ++m)
            acc = __builtin_amdgcn_fdot2(hp[m], vh[m], acc, false);
        red[g][lane] = acc;
        __syncthreads();                 // red ready
        rv = red[0][lane] + red[1][lane] + red[2][lane] + red[3][lane]
           + red[4][lane] + red[5][lane] + red[6][lane] + red[7][lane];
        base += (size_t)B_SZ * DH;
    }
}

// ---------------------------------------------------------------------------
// K3: out[tb, n] = sum_k hid[tb,k] * Wo[n,k] + bo[n]
// ---------------------------------------------------------------------------
__global__ __launch_bounds__(256) void k3_out(
    const float* __restrict__ hid, const float* __restrict__ Wo,
    const float* __restrict__ bo, float* __restrict__ out)
{
    __shared__ float At[64][136];
    __shared__ float Bt[64][68];
    const int m0 = blockIdx.y * 128;
    const int n0 = blockIdx.x * 64;
    const int tid = threadIdx.x;
    const int tx = tid & 15, ty = tid >> 4;
    float acc[8][4] = {};

    for (int kc = 0; kc < DH; kc += 64) {
        #pragma unroll
        for (int i = 0; i < 8; ++i) {
            int idx = tid + i * 256;
            int row = idx >> 4;
            int c4  = idx & 15;
            float4 v = *reinterpret_cast<const float4*>(&hid[(size_t)(m0 + row) * DH + kc + c4 * 4]);
            At[c4*4+0][row] = v.x; At[c4*4+1][row] = v.y;
            At[c4*4+2][row] = v.z; At[c4*4+3][row] = v.w;
        }
        #pragma unroll
        for (int i = 0; i < 4; ++i) {
            int idx = tid + i * 256;
            int row = idx >> 4;
            int c4  = idx & 15;
            float4 v = *reinterpret_cast<const float4*>(&Wo[(size_t)(n0 + row) * DH + kc + c4 * 4]);
            Bt[c4*4+0][row] = v.x; Bt[c4*4+1][row] = v.y;
            Bt[c4*4+2][row] = v.z; Bt[c4*4+3][row] = v.w;
        }
        __syncthreads();
        #pragma unroll
        for (int k = 0; k < 64; ++k) {
            float4 a0 = *reinterpret_cast<const float4*>(&At[k][ty * 8]);
            float4 a1 = *reinterpret_cast<const float4*>(&At[k][ty * 8 + 4]);
            float4 b  = *reinterpret_cast<const float4*>(&Bt[k][tx * 4]);
            float av[8] = {a0.x, a0.y, a0.z, a0.w, a1.x, a1.y, a1.z, a1.w};
            float bv[4] = {b.x, b.y, b.z, b.w};
            #pragma unroll
            for (int i = 0; i < 8; ++i)
                #pragma unroll
                for (int j = 0; j < 4; ++j)
                    acc[i][j] = fmaf(av[i], bv[j], acc[i][j]);
        }
        __syncthreads();
    }
    float4 bias = *reinterpret_cast<const float4*>(&bo[n0 + tx * 4]);
    #pragma unroll
    for (int i = 0; i < 8; ++i) {
        float4 o;
        o.x = acc[i][0] + bias.x; o.y = acc[i][1] + bias.y;
        o.z = acc[i][2] + bias.z; o.w = acc[i][3] + bias.w;
        *reinterpret_cast<float4*>(&out[(size_t)(m0 + ty * 8 + i) * DOUT + n0 + tx * 4]) = o;
    }
}

// ---------------------------------------------------------------------------
extern "C" void kernel_launch(void* const* d_in, const int* in_sizes, int n_in,
                              void* d_out, int out_size, void* d_ws, size_t ws_size,
                              hipStream_t stream)
{
    const float* x  = (const float*)d_in[0];
    const float* Wi = (const float*)d_in[1];
    const float* U  = (const float*)d_in[2];
    const float* V  = (const float*)d_in[3];
    const float* bh = (const float*)d_in[4];
    const float* Wo = (const float*)d_in[5];
    const float* bo = (const float*)d_in[6];
    float* hid  = (float*)d_out;              // hidden region, also zi staging
    float* outp = (float*)d_out + HID_ELEMS;  // output region

    k1_zi<<<dim3(DH / 64, (T_STEPS * B_SZ) / 64), 256, 0, stream>>>(x, Wi, bh, hid);
    k2_rec<<<dim3(B_SZ), 512, 0, stream>>>(U, V, hid);
    k3_out<<<dim3(DOUT / 64, (T_STEPS * B_SZ) / 128), 256, 0, stream>>>(hid, Wo, bo, outp);
}

// Round 9
// 998.592 us; speedup vs baseline: 1.9263x; 1.3022x over previous
//
#include <hip/hip_runtime.h>

#define T_STEPS 512
#define B_SZ    64
#define DIN     128
#define DH      1024
#define DOUT    256
#define RNK     64
#define HID_ELEMS ((size_t)T_STEPS * B_SZ * DH)   // 33554432

typedef _Float16 h2  __attribute__((ext_vector_type(2)));
typedef _Float16 h8v __attribute__((ext_vector_type(8)));
typedef short    s8v __attribute__((ext_vector_type(8)));
typedef float    f4v __attribute__((ext_vector_type(4)));

// barrier that does NOT drain vmcnt: global stores / prefetch stay in flight
#define WGBAR() asm volatile("s_waitcnt lgkmcnt(0)\n\ts_barrier" ::: "memory")

static __device__ __forceinline__ unsigned short f2bf(float f) {
    unsigned u = __float_as_uint(f);
    unsigned r = (u + 0x7FFFu + ((u >> 16) & 1u)) >> 16;   // RNE
    return (unsigned short)r;
}

// ---------------------------------------------------------------------------
// K0: Wo fp32 -> bf16 into workspace (one-time, 512 KB)
// ---------------------------------------------------------------------------
__global__ __launch_bounds__(256) void k0_cvt(
    const float* __restrict__ Wo, unsigned short* __restrict__ Wo16)
{
    int i = (blockIdx.x * 256 + threadIdx.x) * 4;   // 65536 threads x 4 = 262144
    float4 v = *reinterpret_cast<const float4*>(&Wo[i]);
    ushort4 o;
    o.x = f2bf(v.x); o.y = f2bf(v.y); o.z = f2bf(v.z); o.w = f2bf(v.w);
    *reinterpret_cast<ushort4*>(&Wo16[i]) = o;
}

// ---------------------------------------------------------------------------
// K1: zi[tb, h] = sum_k x[tb,k] * Wi[h,k] + bh[h]   -> stored into hidden region
// ---------------------------------------------------------------------------
__global__ __launch_bounds__(256) void k1_zi(
    const float* __restrict__ x, const float* __restrict__ Wi,
    const float* __restrict__ bh, float* __restrict__ zi)
{
    __shared__ float At[64][68];
    __shared__ float Bt[64][68];
    const int m0 = blockIdx.y * 64;
    const int n0 = blockIdx.x * 64;
    const int tid = threadIdx.x;
    const int tx = tid & 15, ty = tid >> 4;
    float acc[4][4] = {};

    for (int kc = 0; kc < DIN; kc += 64) {
        #pragma unroll
        for (int i = 0; i < 4; ++i) {
            int idx = tid + i * 256;
            int row = idx >> 4;
            int c4  = idx & 15;
            float4 v = *reinterpret_cast<const float4*>(&x[(size_t)(m0 + row) * DIN + kc + c4 * 4]);
            At[c4*4+0][row] = v.x; At[c4*4+1][row] = v.y;
            At[c4*4+2][row] = v.z; At[c4*4+3][row] = v.w;
        }
        #pragma unroll
        for (int i = 0; i < 4; ++i) {
            int idx = tid + i * 256;
            int row = idx >> 4;
            int c4  = idx & 15;
            float4 v = *reinterpret_cast<const float4*>(&Wi[(size_t)(n0 + row) * DIN + kc + c4 * 4]);
            Bt[c4*4+0][row] = v.x; Bt[c4*4+1][row] = v.y;
            Bt[c4*4+2][row] = v.z; Bt[c4*4+3][row] = v.w;
        }
        __syncthreads();
        #pragma unroll
        for (int k = 0; k < 64; ++k) {
            float4 a = *reinterpret_cast<const float4*>(&At[k][ty * 4]);
            float4 b = *reinterpret_cast<const float4*>(&Bt[k][tx * 4]);
            float av[4] = {a.x, a.y, a.z, a.w};
            float bv[4] = {b.x, b.y, b.z, b.w};
            #pragma unroll
            for (int i = 0; i < 4; ++i)
                #pragma unroll
                for (int j = 0; j < 4; ++j)
                    acc[i][j] = fmaf(av[i], bv[j], acc[i][j]);
        }
        __syncthreads();
    }
    float4 bias = *reinterpret_cast<const float4*>(&bh[n0 + tx * 4]);
    #pragma unroll
    for (int i = 0; i < 4; ++i) {
        float4 o;
        o.x = acc[i][0] + bias.x; o.y = acc[i][1] + bias.y;
        o.z = acc[i][2] + bias.z; o.w = acc[i][3] + bias.w;
        *reinterpret_cast<float4*>(&zi[(size_t)(m0 + ty * 4 + i) * DH + n0 + tx * 4]) = o;
    }
}

// ---------------------------------------------------------------------------
// K2 v3: register-resident weights, no-spill launch bounds, lgkm-only barriers,
// 4-way split dependent chains, b128 LDS reads.
// ---------------------------------------------------------------------------
__global__ __launch_bounds__(512, 1) void k2_rec(
    const float* __restrict__ U, const float* __restrict__ V,
    float* __restrict__ hid)
{
    __shared__ _Float16 h16[DH];
    __shared__ float red[8][64];
    const int b    = blockIdx.x;
    const int tid  = threadIdx.x;
    const int lane = tid & 63;
    const int g    = tid >> 6;          // wave id 0..7
    const int j0   = tid, j1 = tid + 512;

    // ---- one-time: weights into registers ----
    float u0[64], u1[64];
    const float4* __restrict__ U4 = reinterpret_cast<const float4*>(U);
    #pragma unroll
    for (int q = 0; q < 16; ++q) {
        float4 a = U4[j0 * 16 + q];
        u0[q*4+0]=a.x; u0[q*4+1]=a.y; u0[q*4+2]=a.z; u0[q*4+3]=a.w;
        float4 c = U4[j1 * 16 + q];
        u1[q*4+0]=c.x; u1[q*4+1]=c.y; u1[q*4+2]=c.z; u1[q*4+3]=c.w;
    }
    h2 vh[64];                           // V[lane][g*128 + 2m .. +1], packed fp16
    {
        const float2* __restrict__ vrow =
            reinterpret_cast<const float2*>(V + (size_t)lane * DH + g * 128);
        #pragma unroll
        for (int m = 0; m < 64; ++m) {
            float2 f = vrow[m];
            h2 p; p.x = (_Float16)f.x; p.y = (_Float16)f.y;
            vh[m] = p;
        }
    }

    float rv = 0.0f;                     // lane l holds r_l (h0 = 0 -> r = 0)
    size_t base = (size_t)b * DH;
    float z0 = hid[base + j0];           // zi + bh for t = 0
    float z1 = hid[base + j1];

    for (int t = 0; t < T_STEPS; ++t) {
        // expand: e_j = zi_j + sum_k r_k * U[j,k]  (fp32, 4 split chains)
        float e0p[4] = {z0, 0.f, 0.f, 0.f};
        float e1p[4] = {z1, 0.f, 0.f, 0.f};
        #pragma unroll
        for (int kk = 0; kk < 64; ++kk) {
            float rk = __uint_as_float(__builtin_amdgcn_readlane(__float_as_uint(rv), kk));
            e0p[kk & 3] = fmaf(rk, u0[kk], e0p[kk & 3]);
            e1p[kk & 3] = fmaf(rk, u1[kk], e1p[kk & 3]);
        }
        float h0 = fmaxf((e0p[0] + e0p[1]) + (e0p[2] + e0p[3]), 0.0f);
        float h1 = fmaxf((e1p[0] + e1p[1]) + (e1p[2] + e1p[3]), 0.0f);

        // prefetch next zi first (so its wait is vmcnt(>0) before the stores)
        size_t nbase = base + (size_t)B_SZ * DH;
        float nz0 = hid[nbase + j0];     // t=511 reads out-region: unused, safe
        float nz1 = hid[nbase + j1];

        hid[base + j0] = h0;             // hidden output (fire-and-forget)
        hid[base + j1] = h1;
        h16[j0] = (_Float16)h0;          // LDS exchange for contract
        h16[j1] = (_Float16)h1;

        WGBAR();                         // lgkmcnt(0) + s_barrier (no vm drain)

        // contract: wave g, lane k: a = sum_{jj<128} h[g*128+jj] * V[k][g*128+jj]
        float ap[4] = {0.f, 0.f, 0.f, 0.f};
        const h8v* __restrict__ hp8 = reinterpret_cast<const h8v*>(&h16[g * 128]);
        #pragma unroll
        for (int q = 0; q < 16; ++q) {
            h8v hv = hp8[q];             // one ds_read_b128, broadcast addr
            h2 p0; p0.x = hv[0]; p0.y = hv[1];
            h2 p1; p1.x = hv[2]; p1.y = hv[3];
            h2 p2; p2.x = hv[4]; p2.y = hv[5];
            h2 p3; p3.x = hv[6]; p3.y = hv[7];
            ap[0] = __builtin_amdgcn_fdot2(p0, vh[q*4+0], ap[0], false);
            ap[1] = __builtin_amdgcn_fdot2(p1, vh[q*4+1], ap[1], false);
            ap[2] = __builtin_amdgcn_fdot2(p2, vh[q*4+2], ap[2], false);
            ap[3] = __builtin_amdgcn_fdot2(p3, vh[q*4+3], ap[3], false);
        }
        red[g][lane] = (ap[0] + ap[1]) + (ap[2] + ap[3]);

        WGBAR();                         // red ready

        rv = ((red[0][lane] + red[1][lane]) + (red[2][lane] + red[3][lane]))
           + ((red[4][lane] + red[5][lane]) + (red[6][lane] + red[7][lane]));
        z0 = nz0; z1 = nz1;
        base = nbase;
    }
}

// ---------------------------------------------------------------------------
// K3 v2: bf16 MFMA GEMM. out[32768,256] = hid @ Wo.T + bo.
// Tile BM=128, BN=128, BK=64; 4 waves in 2x2; 4x4 16x16 frags per wave.
// A (hid) converted fp32->bf16 while staging; B (Wo) pre-converted in ws.
// Frag layouts (gfx950 16x16x32): A/B lane l: row/col = l&15, k = (l>>4)*8+i.
// C/D: col = l&15, row = (l>>4)*4 + reg.
// ---------------------------------------------------------------------------
__global__ __launch_bounds__(256, 1) void k3_out(
    const float* __restrict__ hid, const unsigned short* __restrict__ Wo16,
    const float* __restrict__ bo, float* __restrict__ out)
{
    __shared__ unsigned short As[128][72];   // 72-elem stride: 144B, 16B-aligned
    __shared__ unsigned short Bs[128][72];
    const int tid = threadIdx.x;
    const int w  = tid >> 6, l = tid & 63;
    const int wr = w >> 1,  wc = w & 1;
    const int m0 = blockIdx.x * 128;
    const int n0 = blockIdx.y * 128;
    const int fr = l & 15;        // frag row/col index
    const int fg = l >> 4;        // k-group
    f4v acc[4][4] = {};

    for (int kc = 0; kc < DH; kc += 64) {
        __syncthreads();          // previous compute done before LDS overwrite
        // stage A: 128 rows x 64 k, fp32 -> bf16
        #pragma unroll
        for (int uu = 0; uu < 4; ++uu) {
            int u = tid + uu * 256;               // 0..1023
            int row = u >> 3, ks = u & 7;
            const float4* src = reinterpret_cast<const float4*>(
                &hid[(size_t)(m0 + row) * DH + kc + ks * 8]);
            float4 a = src[0], bqq = src[1];
            s8v t;
            t[0] = (short)f2bf(a.x);  t[1] = (short)f2bf(a.y);
            t[2] = (short)f2bf(a.z);  t[3] = (short)f2bf(a.w);
            t[4] = (short)f2bf(bqq.x); t[5] = (short)f2bf(bqq.y);
            t[6] = (short)f2bf(bqq.z); t[7] = (short)f2bf(bqq.w);
            *reinterpret_cast<s8v*>(&As[row][ks * 8]) = t;
        }
        // stage B: 128 rows x 64 k, already bf16
        #pragma unroll
        for (int uu = 0; uu < 4; ++uu) {
            int u = tid + uu * 256;
            int row = u >> 3, ks = u & 7;
            s8v v = *reinterpret_cast<const s8v*>(
                &Wo16[(size_t)(n0 + row) * DH + kc + ks * 8]);
            *reinterpret_cast<s8v*>(&Bs[row][ks * 8]) = v;
        }
        __syncthreads();
        #pragma unroll
        for (int kk = 0; kk < 64; kk += 32) {
            s8v af[4], bf[4];
            #pragma unroll
            for (int i = 0; i < 4; ++i)
                af[i] = *reinterpret_cast<const s8v*>(&As[wr*64 + i*16 + fr][kk + fg*8]);
            #pragma unroll
            for (int i = 0; i < 4; ++i)
                bf[i] = *reinterpret_cast<const s8v*>(&Bs[wc*64 + i*16 + fr][kk + fg*8]);
            #pragma unroll
            for (int mi = 0; mi < 4; ++mi)
                #pragma unroll
                for (int ni = 0; ni < 4; ++ni)
                    acc[mi][ni] = __builtin_amdgcn_mfma_f32_16x16x32_bf16(
                        af[mi], bf[ni], acc[mi][ni], 0, 0, 0);
        }
    }
    // epilogue: C frag -> out (+bias)
    #pragma unroll
    for (int ni = 0; ni < 4; ++ni) {
        int col = n0 + wc*64 + ni*16 + fr;
        float bias = bo[col];
        #pragma unroll
        for (int mi = 0; mi < 4; ++mi) {
            #pragma unroll
            for (int r = 0; r < 4; ++r) {
                int row = m0 + wr*64 + mi*16 + fg*4 + r;
                out[(size_t)row * DOUT + col] = acc[mi][ni][r] + bias;
            }
        }
    }
}

// ---------------------------------------------------------------------------
extern "C" void kernel_launch(void* const* d_in, const int* in_sizes, int n_in,
                              void* d_out, int out_size, void* d_ws, size_t ws_size,
                              hipStream_t stream)
{
    const float* x  = (const float*)d_in[0];
    const float* Wi = (const float*)d_in[1];
    const float* U  = (const float*)d_in[2];
    const float* V  = (const float*)d_in[3];
    const float* bh = (const float*)d_in[4];
    const float* Wo = (const float*)d_in[5];
    const float* bo = (const float*)d_in[6];
    float* hid  = (float*)d_out;              // hidden region, also zi staging
    float* outp = (float*)d_out + HID_ELEMS;  // output region
    unsigned short* Wo16 = (unsigned short*)d_ws;  // 512 KB

    k0_cvt<<<dim3(DOUT * DH / (256 * 4)), 256, 0, stream>>>(Wo, Wo16);
    k1_zi<<<dim3(DH / 64, (T_STEPS * B_SZ) / 64), 256, 0, stream>>>(x, Wi, bh, hid);
    k2_rec<<<dim3(B_SZ), 512, 0, stream>>>(U, V, hid);
    k3_out<<<dim3((T_STEPS * B_SZ) / 128, DOUT / 128), 256, 0, stream>>>(hid, Wo16, bo, outp);
}